// Round 10
// baseline (275.007 us; speedup 1.0000x reference)
//
#include <hip/hip_runtime.h>
#include <math.h>

// LSTM autoencoder, single timestep, h0=c0=0.
// => whh unused; f-gate unused (f*c0==0).
// ROLLING PIPELINE, single kernel: one phase per block (phase = blockIdx>>9,
// 512 blocks per phase x 7 phases = 3584 blocks). Each block waits (leader
// poll, s_sleep backoff) on the producer phase's completion counter, stages
// the input vector to LDS, computes 8 row-tasks, stores h via agent-scope
// relaxed atomics (no cache maintenance), then release-adds the phase
// counter (one RMW per block). Blocks retire after one phase => the HW
// dispatcher overlaps next-phase spawn with current-phase drain; no global
// barriers, no launch gaps.

#define NT 512
#define NWAVE 8
#define PBLK 512                 // blocks per phase
#define PAD 32                   // u32 per counter line (128 B)

typedef float v4f __attribute__((ext_vector_type(4)));

__device__ __forceinline__ float sigmoidf_(float v) {
    return 1.0f / (1.0f + expf(-v));
}

__device__ __forceinline__ float wred(float v) {
    #pragma unroll
    for (int off = 32; off > 0; off >>= 1) v += __shfl_xor(v, off, 64);
    return v;
}

__device__ __forceinline__ void st_agent(float* p, float v) {
    __hip_atomic_store(p, v, __ATOMIC_RELAXED, __HIP_MEMORY_SCOPE_AGENT);
}

__device__ __forceinline__ unsigned long long aload64(const float* p) {
    return __hip_atomic_load((const unsigned long long*)p,
                             __ATOMIC_RELAXED, __HIP_MEMORY_SCOPE_AGENT);
}

// Leader polls producer counter until all PBLK producer blocks reported.
__device__ __forceinline__ void wait_flag(const unsigned* c) {
    if (threadIdx.x == 0) {
        if (__hip_atomic_load(c, __ATOMIC_RELAXED, __HIP_MEMORY_SCOPE_AGENT) < PBLK) {
            __builtin_amdgcn_s_sleep(8);
            while (__hip_atomic_load(c, __ATOMIC_RELAXED, __HIP_MEMORY_SCOPE_AGENT) < PBLK)
                __builtin_amdgcn_s_sleep(32);
        }
    }
    __builtin_amdgcn_sched_barrier(0);
    __syncthreads();
}

// Block reports completion: one release RMW per block (after __syncthreads
// has drained vmcnt, so all of the block's h-stores are at the coherence pt).
__device__ __forceinline__ void done_flag(unsigned* c) {
    __syncthreads();
    if (threadIdx.x == 0)
        __hip_atomic_fetch_add(c, 1u, __ATOMIC_RELEASE, __HIP_MEMORY_SCOPE_AGENT);
}

// Stage phase input into LDS. ATOMIC=true: agent-scope 8B atomic loads.
template<int N, bool ATOMIC>
__device__ __forceinline__ void stage(const float* __restrict__ g, float* xs) {
    if constexpr (ATOMIC) {
        for (int i = threadIdx.x * 2; i < N; i += NT * 2) {
            union { unsigned long long u; float f[2]; } c;
            c.u = aload64(g + i);
            xs[i] = c.f[0]; xs[i + 1] = c.f[1];
        }
    } else {
        for (int i = threadIdx.x * 4; i < N; i += NT * 4)
            *reinterpret_cast<v4f*>(xs + i) = *reinterpret_cast<const v4f*>(g + i);
    }
    __syncthreads();
}

// CLEN multiple of 256.
template<int CLEN>
__device__ __forceinline__ void dot3(const float* __restrict__ wi,
                                     const float* __restrict__ wg,
                                     const float* __restrict__ wo,
                                     const float* __restrict__ xs,
                                     int lane, float& si, float& sg, float& so) {
    si = 0.f; sg = 0.f; so = 0.f;
    #pragma unroll 4
    for (int c0 = 0; c0 < CLEN; c0 += 256) {
        const int c = c0 + lane * 4;
        const v4f xv = *reinterpret_cast<const v4f*>(xs + c);
        const v4f av = *reinterpret_cast<const v4f*>(wi + c);
        const v4f gv = *reinterpret_cast<const v4f*>(wg + c);
        const v4f ov = *reinterpret_cast<const v4f*>(wo + c);
        si += av.x * xv.x + av.y * xv.y + av.z * xv.z + av.w * xv.w;
        sg += gv.x * xv.x + gv.y * xv.y + gv.z * xv.z + gv.w * xv.w;
        so += ov.x * xv.x + ov.y * xv.y + ov.z * xv.z + ov.w * xv.w;
    }
}

__device__ __forceinline__ void epi(float si, float sg, float so,
                                    const float* __restrict__ bi,
                                    const float* __restrict__ bh,
                                    int j, int dh, float* __restrict__ h) {
    const float gi = si + bi[j]          + bh[j];
    const float gg = sg + bi[j + 2 * dh] + bh[j + 2 * dh];
    const float go = so + bi[j + 3 * dh] + bh[j + 3 * dh];
    st_agent(h + j, sigmoidf_(go) * tanhf(sigmoidf_(gi) * tanhf(gg)));
}

// One LSTM phase; this block handles wave-tasks wv = pb*8+wl of 4096.
// SPLIT waves share a row (column split, LDS combine).
template<int C, int SPLIT>
__device__ __forceinline__ void cell(const float* __restrict__ w,
                                     const float* __restrict__ bi,
                                     const float* __restrict__ bh,
                                     const float* __restrict__ xs,
                                     float* __restrict__ h,
                                     int dh, int wv, int wl, int lane,
                                     float (*red)[3]) {
    constexpr int CL = C / SPLIT;
    const int j = wv / SPLIT;
    const int part = wv % SPLIT;
    const int off = part * CL;
    const float* wi = w + (size_t)j * C + off;
    const float* wg = w + ((size_t)j + 2u * (size_t)dh) * C + off;
    const float* wo = w + ((size_t)j + 3u * (size_t)dh) * C + off;
    float si, sg, so;
    dot3<CL>(wi, wg, wo, xs + off, lane, si, sg, so);
    si = wred(si); sg = wred(sg); so = wred(so);
    if constexpr (SPLIT > 1) {
        if (lane == 0) { red[wl][0] = si; red[wl][1] = sg; red[wl][2] = so; }
        __syncthreads();
        if (part == 0 && lane == 0) {
            #pragma unroll
            for (int k = 1; k < SPLIT; ++k) {
                si += red[wl + k][0]; sg += red[wl + k][1]; so += red[wl + k][2];
            }
            epi(si, sg, so, bi, bh, j, dh, h);
        }
    } else {
        if (lane == 0) epi(si, sg, so, bi, bh, j, dh, h);
    }
}

// Final linear: 4096 rows, 1 row/wave, C=2048. Plain stores to d_out.
__device__ __forceinline__ void linear1(const float* __restrict__ w,
                                        const float* __restrict__ b,
                                        const float* __restrict__ xs,
                                        float* __restrict__ y,
                                        int wv, int lane) {
    const float* wr = w + (size_t)wv * 2048;
    float s = 0.f;
    #pragma unroll 4
    for (int c0 = 0; c0 < 2048; c0 += 256) {
        const int c = c0 + lane * 4;
        const v4f xv = *reinterpret_cast<const v4f*>(xs + c);
        const v4f a  = *reinterpret_cast<const v4f*>(wr + c);
        s += a.x * xv.x + a.y * xv.y + a.z * xv.z + a.w * xv.w;
    }
    s = wred(s);
    if (lane == 0) y[wv] = s + b[wv];
}

struct Params {
    const float *x;
    const float *w0, *bi0, *bh0;  // e1l0: 2048 rows, C=4096
    const float *w1, *bi1, *bh1;  // e1l1: 2048, C=2048
    const float *w2, *bi2, *bh2;  // e2:   1024, C=2048
    const float *w3, *bi3, *bh3;  // d1l0: 1024, C=1024
    const float *w4, *bi4, *bh4;  // d1l1: 1024, C=1024
    const float *w5, *bi5, *bh5;  // d2:   2048, C=1024
    const float *ow, *ob;         // out:  4096, C=2048
    float *out;
    float *ws;
};

__global__ __launch_bounds__(NT) void fused_lstm_ae(Params p) {
    __shared__ float xs[4096];
    __shared__ float red[NWAVE][3];
    const int lane  = threadIdx.x & 63;
    const int wl    = threadIdx.x >> 6;
    const int phase = (int)blockIdx.x >> 9;     // 512 blocks per phase
    const int pb    = (int)blockIdx.x & 511;
    const int wv    = pb * NWAVE + wl;          // 0..4095

    unsigned* cnt = (unsigned*)p.ws;            // 7 padded lines, zeroed
    float* h1 = p.ws + 4096;   // 2048
    float* h2 = h1 + 2048;     // 2048
    float* z  = h2 + 2048;     // 1024
    float* h3 = z  + 1024;     // 1024
    float* h4 = h3 + 1024;     // 1024
    float* h5 = h4 + 1024;     // 2048

    switch (phase) {
    case 0:
        stage<4096, false>(p.x, xs);
        cell<4096, 2>(p.w0, p.bi0, p.bh0, xs, h1, 2048, wv, wl, lane, red);
        done_flag(cnt + 0 * PAD);
        break;
    case 1:
        wait_flag(cnt + 0 * PAD);
        stage<2048, true>(h1, xs);
        cell<2048, 2>(p.w1, p.bi1, p.bh1, xs, h2, 2048, wv, wl, lane, red);
        done_flag(cnt + 1 * PAD);
        break;
    case 2:
        wait_flag(cnt + 1 * PAD);
        stage<2048, true>(h2, xs);
        cell<2048, 4>(p.w2, p.bi2, p.bh2, xs, z, 1024, wv, wl, lane, red);
        done_flag(cnt + 2 * PAD);
        break;
    case 3:
        wait_flag(cnt + 2 * PAD);
        stage<1024, true>(z, xs);
        cell<1024, 4>(p.w3, p.bi3, p.bh3, xs, h3, 1024, wv, wl, lane, red);
        done_flag(cnt + 3 * PAD);
        break;
    case 4:
        wait_flag(cnt + 3 * PAD);
        stage<1024, true>(h3, xs);
        cell<1024, 4>(p.w4, p.bi4, p.bh4, xs, h4, 1024, wv, wl, lane, red);
        done_flag(cnt + 4 * PAD);
        break;
    case 5:
        wait_flag(cnt + 4 * PAD);
        stage<1024, true>(h4, xs);
        cell<1024, 2>(p.w5, p.bi5, p.bh5, xs, h5, 2048, wv, wl, lane, red);
        done_flag(cnt + 5 * PAD);
        break;
    default:
        wait_flag(cnt + 5 * PAD);
        stage<2048, true>(h5, xs);
        linear1(p.ow, p.ob, xs, p.out, wv, lane);
        break;
    }
}

extern "C" void kernel_launch(void* const* d_in, const int* in_sizes, int n_in,
                              void* d_out, int out_size, void* d_ws, size_t ws_size,
                              hipStream_t stream)
{
    Params p;
    p.x   = (const float*)d_in[0];
    p.w0  = (const float*)d_in[1];
    p.bi0 = (const float*)d_in[3];
    p.bh0 = (const float*)d_in[4];
    p.w1  = (const float*)d_in[5];
    p.bi1 = (const float*)d_in[7];
    p.bh1 = (const float*)d_in[8];
    p.w2  = (const float*)d_in[9];
    p.bi2 = (const float*)d_in[11];
    p.bh2 = (const float*)d_in[12];
    p.w3  = (const float*)d_in[13];
    p.bi3 = (const float*)d_in[15];
    p.bh3 = (const float*)d_in[16];
    p.w4  = (const float*)d_in[17];
    p.bi4 = (const float*)d_in[19];
    p.bh4 = (const float*)d_in[20];
    p.w5  = (const float*)d_in[21];
    p.bi5 = (const float*)d_in[23];
    p.bh5 = (const float*)d_in[24];
    p.ow  = (const float*)d_in[25];
    p.ob  = (const float*)d_in[26];
    p.out = (float*)d_out;
    p.ws  = (float*)d_ws;

    // Zero the 7 phase counters (must not persist across graph replays).
    hipMemsetAsync(d_ws, 0, 1024, stream);

    fused_lstm_ae<<<7 * PBLK, NT, 0, stream>>>(p);
}

// Round 11
// 59.736 us; speedup vs baseline: 4.6037x; 4.6037x over previous
//
#include <hip/hip_runtime.h>
#include <math.h>

// LSTM autoencoder, single timestep, h0=c0=0.
// => whh matrices unused; f-gate unused (f*c0 == 0).
// 7 plain kernels (graph-captured). 512-thread blocks (8 waves); every row's
// dot product is column-split across SPLIT waves (LDS combine) so each phase
// launches up to 8192 waves (32 waves/CU) for maximum loads-in-flight.
// R10 verdict: all fused single-kernel variants (grid barrier, hierarchical
// fence-free barrier, dataflow flags, rolling pipeline) measured WORSE than
// this structure; cross-workgroup ordering costs >= a graph kernel boundary.

__device__ __forceinline__ float sigmoidf_(float v) {
    return 1.0f / (1.0f + expf(-v));
}

__device__ __forceinline__ float wred(float v) {
    #pragma unroll
    for (int off = 32; off > 0; off >>= 1) v += __shfl_xor(v, off, 64);
    return v;
}

// CLEN must be a multiple of 256.
template<int CLEN>
__device__ __forceinline__ void dot3(const float* __restrict__ wi,
                                     const float* __restrict__ wg,
                                     const float* __restrict__ wo,
                                     const float* __restrict__ x,
                                     int lane, float& si, float& sg, float& so) {
    si = 0.f; sg = 0.f; so = 0.f;
    #pragma unroll 4
    for (int c0 = 0; c0 < CLEN; c0 += 256) {
        const int c = c0 + lane * 4;
        const float4 xv = *reinterpret_cast<const float4*>(x + c);
        const float4 av = *reinterpret_cast<const float4*>(wi + c);
        const float4 gv = *reinterpret_cast<const float4*>(wg + c);
        const float4 ov = *reinterpret_cast<const float4*>(wo + c);
        si += av.x * xv.x + av.y * xv.y + av.z * xv.z + av.w * xv.w;
        sg += gv.x * xv.x + gv.y * xv.y + gv.z * xv.z + gv.w * xv.w;
        so += ov.x * xv.x + ov.y * xv.y + ov.z * xv.z + ov.w * xv.w;
    }
}

__device__ __forceinline__ void epilogue(float si, float sg, float so,
                                         const float* __restrict__ bi,
                                         const float* __restrict__ bh,
                                         int j, int dh, float* __restrict__ h) {
    const float gi = si + bi[j]          + bh[j];
    const float gg = sg + bi[j + 2 * dh] + bh[j + 2 * dh];
    const float go = so + bi[j + 3 * dh] + bh[j + 3 * dh];
    const float cc = sigmoidf_(gi) * tanhf(gg);
    h[j] = sigmoidf_(go) * tanhf(cc);
}

// Block = 8 waves (512 threads). SPLIT waves cooperate on one row (column
// split, LDS combine); 8/SPLIT rows per block. Grid = R*SPLIT/8 blocks.
template<int C, int SPLIT>
__global__ __launch_bounds__(512)
void lstm_cell_k(const float* __restrict__ w,
                 const float* __restrict__ bi,
                 const float* __restrict__ bh,
                 const float* __restrict__ x,
                 float* __restrict__ h,
                 int dh)
{
    __shared__ float red[8][3];
    const int lane = threadIdx.x & 63;
    const int wl = threadIdx.x >> 6;
    const int j = (int)blockIdx.x * (8 / SPLIT) + wl / SPLIT;
    const int part = wl % SPLIT;
    constexpr int CL = C / SPLIT;
    const int off = part * CL;

    const float* wi = w + (size_t)j * C + off;
    const float* wg = w + ((size_t)j + 2u * (size_t)dh) * C + off;
    const float* wo = w + ((size_t)j + 3u * (size_t)dh) * C + off;

    float si, sg, so;
    dot3<CL>(wi, wg, wo, x + off, lane, si, sg, so);
    si = wred(si); sg = wred(sg); so = wred(so);

    if (SPLIT > 1) {
        if (lane == 0) { red[wl][0] = si; red[wl][1] = sg; red[wl][2] = so; }
        __syncthreads();
        if (part == 0 && lane == 0) {
            #pragma unroll
            for (int k = 1; k < SPLIT; ++k) {
                si += red[wl + k][0];
                sg += red[wl + k][1];
                so += red[wl + k][2];
            }
            epilogue(si, sg, so, bi, bh, j, dh, h);
        }
    } else {
        if (lane == 0) epilogue(si, sg, so, bi, bh, j, dh, h);
    }
}

// y = W@x + b. SPLIT waves per row, 8/SPLIT rows per block. Grid = R*SPLIT/8.
template<int C, int SPLIT>
__global__ __launch_bounds__(512)
void linear_k(const float* __restrict__ w,
              const float* __restrict__ b,
              const float* __restrict__ x,
              float* __restrict__ y)
{
    __shared__ float red[8];
    const int lane = threadIdx.x & 63;
    const int wl = threadIdx.x >> 6;
    const int j = (int)blockIdx.x * (8 / SPLIT) + wl / SPLIT;
    const int part = wl % SPLIT;
    constexpr int CL = C / SPLIT;
    const int off = part * CL;

    const float* wr = w + (size_t)j * C + off;
    const float* xo = x + off;
    float s = 0.f;
    #pragma unroll 4
    for (int c0 = 0; c0 < CL; c0 += 256) {
        const int c = c0 + lane * 4;
        const float4 xv = *reinterpret_cast<const float4*>(xo + c);
        const float4 wv = *reinterpret_cast<const float4*>(wr + c);
        s += wv.x * xv.x + wv.y * xv.y + wv.z * xv.z + wv.w * xv.w;
    }
    s = wred(s);
    if (SPLIT > 1) {
        if (lane == 0) red[wl] = s;
        __syncthreads();
        if (part == 0 && lane == 0) {
            #pragma unroll
            for (int k = 1; k < SPLIT; ++k) s += red[wl + k];
            y[j] = s + b[j];
        }
    } else {
        if (lane == 0) y[j] = s + b[j];
    }
}

extern "C" void kernel_launch(void* const* d_in, const int* in_sizes, int n_in,
                              void* d_out, int out_size, void* d_ws, size_t ws_size,
                              hipStream_t stream)
{
    const float* x        = (const float*)d_in[0];
    const float* e1l0_wih = (const float*)d_in[1];
    const float* e1l0_bih = (const float*)d_in[3];
    const float* e1l0_bhh = (const float*)d_in[4];
    const float* e1l1_wih = (const float*)d_in[5];
    const float* e1l1_bih = (const float*)d_in[7];
    const float* e1l1_bhh = (const float*)d_in[8];
    const float* e2_wih   = (const float*)d_in[9];
    const float* e2_bih   = (const float*)d_in[11];
    const float* e2_bhh   = (const float*)d_in[12];
    const float* d1l0_wih = (const float*)d_in[13];
    const float* d1l0_bih = (const float*)d_in[15];
    const float* d1l0_bhh = (const float*)d_in[16];
    const float* d1l1_wih = (const float*)d_in[17];
    const float* d1l1_bih = (const float*)d_in[19];
    const float* d1l1_bhh = (const float*)d_in[20];
    const float* d2_wih   = (const float*)d_in[21];
    const float* d2_bih   = (const float*)d_in[23];
    const float* d2_bhh   = (const float*)d_in[24];
    const float* out_w    = (const float*)d_in[25];
    const float* out_b    = (const float*)d_in[26];
    float* out = (float*)d_out;

    float* ws = (float*)d_ws;
    float* h1 = ws;           // 2048
    float* h2 = ws + 2048;    // 2048
    float* z  = ws + 4096;    // 1024
    float* h3 = ws + 5120;    // 1024
    float* h4 = ws + 6144;    // 1024
    float* h5 = ws + 7168;    // 2048

    // Encoder: grids = R*SPLIT/8
    lstm_cell_k<4096, 4><<<1024, 512, 0, stream>>>(e1l0_wih, e1l0_bih, e1l0_bhh, x,  h1, 2048);
    lstm_cell_k<2048, 4><<<1024, 512, 0, stream>>>(e1l1_wih, e1l1_bih, e1l1_bhh, h1, h2, 2048);
    lstm_cell_k<2048, 8><<<1024, 512, 0, stream>>>(e2_wih,   e2_bih,   e2_bhh,   h2, z,  1024);
    // Decoder
    lstm_cell_k<1024, 4><<< 512, 512, 0, stream>>>(d1l0_wih, d1l0_bih, d1l0_bhh, z,  h3, 1024);
    lstm_cell_k<1024, 4><<< 512, 512, 0, stream>>>(d1l1_wih, d1l1_bih, d1l1_bhh, h3, h4, 1024);
    lstm_cell_k<1024, 4><<<1024, 512, 0, stream>>>(d2_wih,   d2_bih,   d2_bhh,   h4, h5, 2048);
    // Output projection
    linear_k<2048, 2><<<1024, 512, 0, stream>>>(out_w, out_b, h5, out);
}